// Round 17
// baseline (136.300 us; speedup 1.0000x reference)
//
#include <hip/hip_runtime.h>
#include <math.h>

#define DM 256
#define SQ 4096
#define BT 2
#define NS 16
#define NTOK (BT*SQ)
#define NCHK 256
#define CHL (SQ/NCHK)

typedef __attribute__((ext_vector_type(8))) short short8;
typedef __attribute__((ext_vector_type(4))) float f32x4;

__device__ __forceinline__ float sigm_(float x){ return 1.f/(1.f+__expf(-x)); }
__device__ __forceinline__ float silu_(float x){ return x*sigm_(x); }
__device__ __forceinline__ float softplus_(float x){ return (x>20.f)? x : log1pf(__expf(x)); }
__device__ __forceinline__ unsigned short f2bf(float f){
  unsigned int u = __float_as_uint(f);
  unsigned int r = (u + 0x7FFFu + ((u>>16)&1u)) >> 16;
  return (unsigned short)r;
}
__device__ __forceinline__ float bf2f(unsigned short u){
  return __uint_as_float(((unsigned int)u)<<16);
}

// ---------- prep: LN+cvt of x | in_proj W cvt | Wcat build | out_proj W cvt ----------
__global__ __launch_bounds__(256) void k_prep(
    const float* __restrict__ x, const float* __restrict__ g, const float* __restrict__ nb,
    unsigned short* __restrict__ xl,
    const float* __restrict__ Win, unsigned short* __restrict__ Wbin,
    const float* __restrict__ xw_f, const float* __restrict__ xw_b,
    const float* __restrict__ dtw_f, const float* __restrict__ dtw_b,
    unsigned short* __restrict__ Wcatb,
    const float* __restrict__ Wout, unsigned short* __restrict__ Wbout)
{
  int bx = blockIdx.x;
  int tid = threadIdx.x;
  if (bx < NTOK/4){
    int tok = bx*4 + (tid>>6);
    int lane = tid & 63;
    const float* row = x + (size_t)tok*DM;
    float4 v = *(const float4*)(row + lane*4);
    float s = v.x+v.y+v.z+v.w;
    float ss = v.x*v.x+v.y*v.y+v.z*v.z+v.w*v.w;
    #pragma unroll
    for (int o=32;o>0;o>>=1){ s += __shfl_xor(s,o,64); ss += __shfl_xor(ss,o,64); }
    float m = s*(1.f/DM);
    float r = rsqrtf(ss*(1.f/DM)-m*m+1e-5f);
    float4 gv = *(const float4*)(g + lane*4);
    float4 bv = *(const float4*)(nb + lane*4);
    ushort4 o4;
    o4.x = f2bf((v.x-m)*r*gv.x+bv.x);
    o4.y = f2bf((v.y-m)*r*gv.y+bv.y);
    o4.z = f2bf((v.z-m)*r*gv.z+bv.z);
    o4.w = f2bf((v.w-m)*r*gv.w+bv.w);
    *(ushort4*)(xl + (size_t)tok*DM + lane*4) = o4;
  } else if (bx < NTOK/4 + 128){
    int i = ((bx - NTOK/4)*256 + tid)*4;
    float4 v = *(const float4*)(Win + i);
    ushort4 o4; o4.x=f2bf(v.x); o4.y=f2bf(v.y); o4.z=f2bf(v.z); o4.w=f2bf(v.w);
    *(ushort4*)(Wbin + i) = o4;
  } else if (bx < NTOK/4 + 136){
    int idx = bx - (NTOK/4 + 128);
    int dir = idx >> 2;
    int kc = (idx & 3)*64;
    const float* xw  = dir? xw_b : xw_f;
    const float* dtw = dir? dtw_b : dtw_f;
    int d = tid;
    float dw[16];
    #pragma unroll
    for (int r=0;r<16;r++) dw[r] = dtw[d*16+r];
    unsigned short* Wd = Wcatb + (size_t)dir*320*DM + (size_t)d*DM + kc;
    for (int kk=0;kk<64;kk++){
      float acc = 0.f;
      #pragma unroll
      for (int r=0;r<16;r++) acc += dw[r]*xw[r*DM + kc + kk];
      Wd[kk] = f2bf(acc);
    }
    if (d < 64){
      unsigned short* Wr = Wcatb + (size_t)dir*320*DM + (size_t)(256+d)*DM + kc;
      if (d < 32){
        const float* src = xw + (size_t)(16+d)*DM + kc;
        for (int kk=0;kk<64;kk++) Wr[kk] = f2bf(src[kk]);
      } else {
        for (int kk=0;kk<64;kk++) Wr[kk] = 0;
      }
    }
  } else {
    int i = ((bx - (NTOK/4 + 136))*256 + tid)*4;
    float4 v = *(const float4*)(Wout + i);
    ushort4 o4; o4.x=f2bf(v.x); o4.y=f2bf(v.y); o4.z=f2bf(v.z); o4.w=f2bf(v.w);
    *(ushort4*)(Wbout + i) = o4;
  }
}

// ---------- in_proj MFMA + fused causal dwconv+silu (y<4) | z bf16 (y>=4) ----------
__global__ __launch_bounds__(256) void k_inproj_conv(
    const unsigned short* __restrict__ xl, const unsigned short* __restrict__ Wb,
    const float* __restrict__ cw_f, const float* __restrict__ cb_f,
    const float* __restrict__ cw_b, const float* __restrict__ cb_b,
    unsigned short* __restrict__ ufb, unsigned short* __restrict__ ubb,
    unsigned short* __restrict__ zb)
{
  __shared__ float xs[134][68];
  __shared__ unsigned short xh[6][256];
  int tid = threadIdx.x;
  int wid = tid >> 6, lane = tid & 63;
  int wm = wid >> 1, wn = wid & 1;
  int row0 = blockIdx.x*128 + wm*64;
  int col0 = blockIdx.y*64 + wn*32;
  int lr = lane & 15, lg = lane >> 4;
  f32x4 acc[4][2];
  #pragma unroll
  for (int m=0;m<4;m++)
    #pragma unroll
    for (int n=0;n<2;n++) acc[m][n] = (f32x4){0.f,0.f,0.f,0.f};

  #pragma unroll
  for (int k0=0;k0<DM;k0+=32){
    short8 a[4], b[2];
    #pragma unroll
    for (int m=0;m<4;m++)
      a[m] = *(const short8*)(xl + (size_t)(row0 + m*16 + lr)*DM + k0 + lg*8);
    #pragma unroll
    for (int n=0;n<2;n++)
      b[n] = *(const short8*)(Wb + (size_t)(col0 + n*16 + lr)*DM + k0 + lg*8);
    #pragma unroll
    for (int m=0;m<4;m++)
      #pragma unroll
      for (int n=0;n<2;n++)
        acc[m][n] = __builtin_amdgcn_mfma_f32_16x16x32_bf16(a[m], b[n], acc[m][n], 0,0,0);
  }
  if (blockIdx.y >= 4){
    int cb = col0 - 256;
    #pragma unroll
    for (int m=0;m<4;m++)
      #pragma unroll
      for (int n=0;n<2;n++)
        #pragma unroll
        for (int r=0;r<4;r++){
          int rr = row0 + m*16 + lg*4 + r;
          int cc = cb + n*16 + lr;
          zb[(size_t)rr*DM + cc] = f2bf(acc[m][n][r]);
        }
    return;
  }
  #pragma unroll
  for (int m=0;m<4;m++)
    #pragma unroll
    for (int n=0;n<2;n++)
      #pragma unroll
      for (int r=0;r<4;r++)
        xs[wm*64 + m*16 + lg*4 + r + 3][wn*32 + n*16 + lr] = acc[m][n][r];
  int b_  = blockIdx.x >> 5;
  int lt0 = (blockIdx.x & 31)*128;
  for (int i=tid; i<6*256; i+=256){
    int hr = i >> 8, k = i & 255;
    int lt = (hr<3)? (lt0-3+hr) : (lt0+128+(hr-3));
    unsigned short v = 0;
    if (lt >= 0 && lt < SQ) v = xl[((size_t)b_*SQ+lt)*DM + k];
    xh[hr][k] = v;
  }
  __syncthreads();
  for (int i=tid; i<384; i+=256){
    int hr = i >> 6, col = i & 63;
    int gcol = blockIdx.y*64 + col;
    float acch = 0.f;
    for (int k=0;k<256;k+=8){
      short8 xa = *(const short8*)&xh[hr][k];
      short8 wv = *(const short8*)(Wb + (size_t)gcol*DM + k);
      #pragma unroll
      for (int e=0;e<8;e++) acch += bf2f((unsigned short)xa[e])*bf2f((unsigned short)wv[e]);
    }
    int xr = (hr<3)? hr : (131 + hr - 3);
    xs[xr][col] = acch;
  }
  __syncthreads();
  int col = tid & 63, tg = tid >> 6;
  int gd = blockIdx.y*64 + col;
  float wf0=cw_f[gd*4], wf1=cw_f[gd*4+1], wf2=cw_f[gd*4+2], wf3=cw_f[gd*4+3];
  float wb0=cw_b[gd*4], wb1=cw_b[gd*4+1], wb2=cw_b[gd*4+2], wb3=cw_b[gd*4+3];
  float bfv = cb_f[gd], bbv = cb_b[gd];
  for (int i=0;i<32;i++){
    int r = tg*32 + i;
    float x0=xs[r][col], x1=xs[r+1][col], x2=xs[r+2][col], x3=xs[r+3][col];
    float vf = silu_(bfv + wf0*x0 + wf1*x1 + wf2*x2 + wf3*x3);
    ufb[((size_t)b_*SQ + lt0 + r)*DM + gd] = f2bf(vf);
    float x4=xs[r+4][col], x5=xs[r+5][col], x6=xs[r+6][col];
    float vb = silu_(bbv + wb3*x3 + wb2*x4 + wb1*x5 + wb0*x6);
    ubb[((size_t)b_*SQ + (SQ-1-(lt0+r)))*DM + gd] = f2bf(vb);
  }
}

// ---------- xproj+dtproj via MFMA: [8192][320] = u_bf16 @ Wcat^T ----------
__global__ __launch_bounds__(256) void k_xproj_mfma(
    const unsigned short* __restrict__ ufb, const unsigned short* __restrict__ ubb,
    const unsigned short* __restrict__ Wcatb,
    const float* __restrict__ dtbias_f, const float* __restrict__ dtbias_b,
    unsigned short* __restrict__ dt16f, unsigned short* __restrict__ dt16b,
    float* __restrict__ bmf, float* __restrict__ cmf,
    float* __restrict__ bmb, float* __restrict__ cmb)
{
  int dir = blockIdx.z;
  const unsigned short* u  = dir? ubb : ufb;
  const unsigned short* Wc = Wcatb + (size_t)dir*320*DM;
  const float* dbi = dir? dtbias_b : dtbias_f;
  unsigned short* dt = dir? dt16b : dt16f;
  float* bm = dir? bmb : bmf;
  float* cm = dir? cmb : cmf;
  int tid = threadIdx.x;
  int wid = tid >> 6, lane = tid & 63;
  int wm = wid >> 1, wn = wid & 1;
  int row0 = blockIdx.x*128 + wm*64;
  int col0 = blockIdx.y*64 + wn*32;
  int lr = lane & 15, lg = lane >> 4;
  f32x4 acc[4][2];
  #pragma unroll
  for (int m=0;m<4;m++)
    #pragma unroll
    for (int n=0;n<2;n++) acc[m][n] = (f32x4){0.f,0.f,0.f,0.f};
  #pragma unroll
  for (int k0=0;k0<DM;k0+=32){
    short8 a[4], b[2];
    #pragma unroll
    for (int m=0;m<4;m++)
      a[m] = *(const short8*)(u + (size_t)(row0 + m*16 + lr)*DM + k0 + lg*8);
    #pragma unroll
    for (int n=0;n<2;n++)
      b[n] = *(const short8*)(Wc + (size_t)(col0 + n*16 + lr)*DM + k0 + lg*8);
    #pragma unroll
    for (int m=0;m<4;m++)
      #pragma unroll
      for (int n=0;n<2;n++)
        acc[m][n] = __builtin_amdgcn_mfma_f32_16x16x32_bf16(a[m], b[n], acc[m][n], 0,0,0);
  }
  if (blockIdx.y < 4){
    #pragma unroll
    for (int n=0;n<2;n++){
      int cc = col0 + n*16 + lr;
      float bias = dbi[cc];
      #pragma unroll
      for (int m=0;m<4;m++)
        #pragma unroll
        for (int r=0;r<4;r++){
          int rr = row0 + m*16 + lg*4 + r;
          dt[(size_t)rr*DM + cc] = f2bf(softplus_(acc[m][n][r] + bias));
        }
    }
  } else if (wn == 0){
    #pragma unroll
    for (int n=0;n<2;n++){
      float* outp = n ? cm : bm;
      #pragma unroll
      for (int m=0;m<4;m++)
        #pragma unroll
        for (int r=0;r<4;r++){
          int rr = row0 + m*16 + lg*4 + r;
          outp[(size_t)rr*NS + lr] = acc[m][n][r];
        }
    }
  }
}

// power-tree: given w, fill e[n] = w^(n+1) for n=0..15 (depth ~3)
__device__ __forceinline__ void pow16_(float w, float* e){
  float w2 = w*w, w4 = w2*w2, w8 = w4*w4;
  float w3 = w2*w;
  e[0]=w;      e[1]=w2;     e[2]=w3;     e[3]=w4;
  e[4]=w4*w;   e[5]=w4*w2;  e[6]=w4*w3;  e[7]=w8;
  e[8]=w8*w;   e[9]=w8*w2;  e[10]=w8*w3; e[11]=w8*w4;
  e[12]=w8*e[4]; e[13]=w8*e[5]; e[14]=w8*e[6]; e[15]=w8*w8;
}

// ---------- scan phase 1: per-chunk summaries (Aprod, h_end) -> bf16 ----------
__global__ __launch_bounds__(256) void k_scan1(
    const unsigned short* __restrict__ dtf, const unsigned short* __restrict__ dtb,
    const unsigned short* __restrict__ ufb, const unsigned short* __restrict__ ubb,
    const float* __restrict__ bmf, const float* __restrict__ bmb,
    const float* __restrict__ alog_f, const float* __restrict__ alog_b,
    unsigned short* __restrict__ apf, unsigned short* __restrict__ hsf,
    unsigned short* __restrict__ apb, unsigned short* __restrict__ hsb)
{
  int c = blockIdx.x, b = blockIdx.y, dir = blockIdx.z;
  const unsigned short* dt = dir? dtb : dtf;
  const unsigned short* u  = dir? ubb : ufb;
  const float* bmp= dir? bmb : bmf;
  const float* al = dir? alog_b : alog_f;
  unsigned short* ap = dir? apb : apf;
  unsigned short* hs = dir? hsb : hsf;
  int d = threadIdx.x;
  __shared__ float sB[CHL*NS];
  for (int i=threadIdx.x;i<CHL*NS;i+=256) sB[i] = bmp[((size_t)b*SQ + c*CHL)*NS + i];
  float A[NS];
  #pragma unroll
  for (int n=0;n<NS;n++) A[n] = -__expf(al[d*NS+n]);
  float A0 = A[0];
  bool pw = true;
  #pragma unroll
  for (int n=0;n<NS;n++)
    pw = pw && (fabsf(A[n] - (float)(n+1)*A0) <= 1e-4f*(float)(n+1)*fabsf(A0));
  float h[NS] = {};
  float dts = 0.f;
  __syncthreads();
  size_t base = ((size_t)b*SQ + c*CHL)*DM + d;
  size_t o = (((size_t)b*NCHK + c)*DM + d)*NS;
  if (pw){
    for (int t=0;t<CHL;t++){
      size_t idx = base + (size_t)t*DM;
      float dtv = bf2f(dt[idx]);
      float uv  = bf2f(u[idx]);
      float du  = dtv*uv;
      dts += dtv;
      float e[NS];
      pow16_(__expf(dtv*A0), e);
      #pragma unroll
      for (int n=0;n<NS;n++) h[n] = h[n]*e[n] + du*sB[t*NS+n];
    }
    // epilogue: ap[n] = exp(A[n]*dts) = w^(n+1), serial power chain (1 exp + 15 muls)
    float w = __expf(A0*dts);
    float accp = 1.f;
    #pragma unroll
    for (int n=0;n<NS;n++){
      accp *= w;
      hs[o+n] = f2bf(h[n]);
      ap[o+n] = f2bf(accp);
    }
  } else {
    for (int t=0;t<CHL;t++){
      size_t idx = base + (size_t)t*DM;
      float dtv = bf2f(dt[idx]);
      float uv  = bf2f(u[idx]);
      float du  = dtv*uv;
      dts += dtv;
      #pragma unroll
      for (int n=0;n<NS;n++) h[n] = h[n]*__expf(dtv*A[n]) + du*sB[t*NS+n];
    }
    #pragma unroll
    for (int n=0;n<NS;n++){ hs[o+n] = f2bf(h[n]); ap[o+n] = f2bf(__expf(A[n]*dts)); }
  }
}

// ---------- scan phase 2: parallel segmented scan (32 chains/block, 8 segments) ----------
__global__ __launch_bounds__(256) void k_scan2(
    const unsigned short* __restrict__ apf, unsigned short* __restrict__ hsf,
    const unsigned short* __restrict__ apb, unsigned short* __restrict__ hsb)
{
  __shared__ float sa[NCHK][32];
  __shared__ float sv[NCHK][32];
  __shared__ float segA[8][32], segV[8][32];
  int bx = blockIdx.x;
  int dg = bx & 127, b = (bx>>7)&1, dir = bx>>8;
  const unsigned short* ap = dir? apb : apf;
  unsigned short* hs = dir? hsb : hsf;
  int dn = threadIdx.x & 31;
  int cg = threadIdx.x >> 5;          // 0..7: segment of 32 chunks
  size_t base = (size_t)b*NCHK*4096 + dg*32 + dn;
  for (int i=0;i<32;i++){
    int c = cg*32 + i;
    size_t idx = base + (size_t)c*4096;
    sa[c][dn] = bf2f(ap[idx]);
    sv[c][dn] = bf2f(hs[idx]);
  }
  __syncthreads();
  float A = 1.f, V = 0.f;
  for (int i=0;i<32;i++){
    int c = cg*32 + i;
    float a = sa[c][dn], v = sv[c][dn];
    V = a*V + v;
    A = A*a;
  }
  segA[cg][dn] = A; segV[cg][dn] = V;
  __syncthreads();
  float pre = 0.f;
  for (int s=0;s<cg;s++) pre = segA[s][dn]*pre + segV[s][dn];
  float xv = pre;
  for (int i=0;i<32;i++){
    int c = cg*32 + i;
    size_t idx = base + (size_t)c*4096;
    hs[idx] = f2bf(xv);
    float a = sa[c][dn], v = sv[c][dn];
    xv = a*xv + v;
  }
}

// ---------- scan phase 3: replay with prefix, emit y bf16 (both dirs, one dispatch) ----------
__global__ __launch_bounds__(256) void k_scan3(
    const unsigned short* __restrict__ dtf, const unsigned short* __restrict__ dtb,
    const unsigned short* __restrict__ ufb, const unsigned short* __restrict__ ubb,
    const float* __restrict__ bmf, const float* __restrict__ bmb,
    const float* __restrict__ cmf, const float* __restrict__ cmb,
    const float* __restrict__ alf, const float* __restrict__ alb,
    const float* __restrict__ Df, const float* __restrict__ Db,
    const unsigned short* __restrict__ zb,
    const unsigned short* __restrict__ hsf, const unsigned short* __restrict__ hsb,
    unsigned short* __restrict__ yf, unsigned short* __restrict__ yb)
{
  int c = blockIdx.x, b = blockIdx.y;
  int dir = blockIdx.z;
  const unsigned short* dt = dir? dtb : dtf;
  const unsigned short* u  = dir? ubb : ufb;
  const float* bmp= dir? bmb : bmf;
  const float* cmp= dir? cmb : cmf;
  const float* al = dir? alb : alf;
  const float* Dv = dir? Db  : Df;
  const unsigned short* hs = dir? hsb : hsf;
  unsigned short* yout = dir? yb : yf;
  int d = threadIdx.x;
  __shared__ float sB[CHL*NS];
  __shared__ float sC[CHL*NS];
  for (int i=threadIdx.x;i<CHL*NS;i+=256){
    sB[i] = bmp[((size_t)b*SQ + c*CHL)*NS + i];
    sC[i] = cmp[((size_t)b*SQ + c*CHL)*NS + i];
  }
  float A[NS], h[NS];
  size_t o = (((size_t)b*NCHK + c)*DM + d)*NS;
  #pragma unroll
  for (int n=0;n<NS;n++){ A[n] = -__expf(al[d*NS+n]); h[n] = bf2f(hs[o+n]); }
  float A0 = A[0];
  bool pw = true;
  #pragma unroll
  for (int n=0;n<NS;n++)
    pw = pw && (fabsf(A[n] - (float)(n+1)*A0) <= 1e-4f*(float)(n+1)*fabsf(A0));
  float Dd = Dv[d];
  __syncthreads();
  if (pw){
    for (int t=0;t<CHL;t++){
      int gt = c*CHL + t;
      size_t idx = ((size_t)b*SQ + gt)*DM + d;
      float dtv = bf2f(dt[idx]);
      float uv  = bf2f(u[idx]);
      float du  = dtv*uv;
      float e[NS];
      pow16_(__expf(dtv*A0), e);
      float y = 0.f;
      #pragma unroll
      for (int n=0;n<NS;n++){
        h[n] = h[n]*e[n] + du*sB[t*NS+n];
        y += h[n]*sC[t*NS+n];
      }
      y += uv*Dd;
      int torig = dir ? (SQ-1-gt) : gt;
      size_t oidx = ((size_t)b*SQ + torig)*DM + d;
      float zv = bf2f(zb[oidx]);
      yout[oidx] = f2bf(y * (zv * sigm_(zv)));
    }
  } else {
    for (int t=0;t<CHL;t++){
      int gt = c*CHL + t;
      size_t idx = ((size_t)b*SQ + gt)*DM + d;
      float dtv = bf2f(dt[idx]);
      float uv  = bf2f(u[idx]);
      float du  = dtv*uv;
      float y = 0.f;
      #pragma unroll
      for (int n=0;n<NS;n++){
        h[n] = h[n]*__expf(dtv*A[n]) + du*sB[t*NS+n];
        y += h[n]*sC[t*NS+n];
      }
      y += uv*Dd;
      int torig = dir ? (SQ-1-gt) : gt;
      size_t oidx = ((size_t)b*SQ + torig)*DM + d;
      float zv = bf2f(zb[oidx]);
      yout[oidx] = f2bf(y * (zv * sigm_(zv)));
    }
  }
}

// ---------- final: y-combine + out-LN (in LDS) + MFMA out_proj + post-LN + skip ----------
#define SOS 266
__global__ __launch_bounds__(256) void k_final2(
    const unsigned short* __restrict__ y16f, const unsigned short* __restrict__ y16b,
    const float* __restrict__ og, const float* __restrict__ ob,
    const unsigned short* __restrict__ Wb,
    const float* __restrict__ pg, const float* __restrict__ pb,
    const float* __restrict__ skip, float* __restrict__ out)
{
  __shared__ unsigned short yn[32][272];
  __shared__ float sOut[32*SOS];
  __shared__ float sm[32], sr[32];
  int tid = threadIdx.x;
  int wid = tid >> 6, lane = tid & 63;
  int row0 = blockIdx.x*32;
  for (int j=0;j<8;j++){
    int rrow = wid*8 + j;
    size_t base = (size_t)(row0+rrow)*DM + lane*4;
    ushort4 hf = *(const ushort4*)(y16f + base);
    ushort4 hb = *(const ushort4*)(y16b + base);
    float4 v;
    v.x = 0.5f*(bf2f(hf.x)+bf2f(hb.x));
    v.y = 0.5f*(bf2f(hf.y)+bf2f(hb.y));
    v.z = 0.5f*(bf2f(hf.z)+bf2f(hb.z));
    v.w = 0.5f*(bf2f(hf.w)+bf2f(hb.w));
    float s = v.x+v.y+v.z+v.w;
    float ss = v.x*v.x+v.y*v.y+v.z*v.z+v.w*v.w;
    #pragma unroll
    for (int o=32;o>0;o>>=1){ s += __shfl_xor(s,o,64); ss += __shfl_xor(ss,o,64); }
    float m = s*(1.f/DM);
    float r = rsqrtf(ss*(1.f/DM)-m*m+1e-5f);
    float4 gv = *(const float4*)(og + lane*4);
    float4 bv = *(const float4*)(ob + lane*4);
    ushort4 o4;
    o4.x = f2bf((v.x-m)*r*gv.x+bv.x);
    o4.y = f2bf((v.y-m)*r*gv.y+bv.y);
    o4.z = f2bf((v.z-m)*r*gv.z+bv.z);
    o4.w = f2bf((v.w-m)*r*gv.w+bv.w);
    *(ushort4*)&yn[rrow][lane*4] = o4;
  }
  __syncthreads();
  int lr = lane & 15, lg = lane >> 4;
  int col0 = wid*64;
  f32x4 acc[2][4];
  #pragma unroll
  for (int m=0;m<2;m++)
    #pragma unroll
    for (int n=0;n<4;n++) acc[m][n] = (f32x4){0.f,0.f,0.f,0.f};
  #pragma unroll
  for (int k0=0;k0<DM;k0+=32){
    short8 a[2], b[4];
    #pragma unroll
    for (int m=0;m<2;m++)
      a[m] = *(const short8*)&yn[m*16 + lr][k0 + lg*8];
    #pragma unroll
    for (int n=0;n<4;n++)
      b[n] = *(const short8*)(Wb + (size_t)(col0 + n*16 + lr)*DM + k0 + lg*8);
    #pragma unroll
    for (int m=0;m<2;m++)
      #pragma unroll
      for (int n=0;n<4;n++)
        acc[m][n] = __builtin_amdgcn_mfma_f32_16x16x32_bf16(a[m], b[n], acc[m][n], 0,0,0);
  }
  #pragma unroll
  for (int m=0;m<2;m++)
    #pragma unroll
    for (int n=0;n<4;n++)
      #pragma unroll
      for (int r=0;r<4;r++)
        sOut[(m*16 + lg*4 + r)*SOS + col0 + n*16 + lr] = acc[m][n][r];
  __syncthreads();
  for (int j=0;j<8;j++){
    int rrow = wid*8 + j;
    const float* rp = &sOut[rrow*SOS + lane*4];
    float2 v0 = *(const float2*)(rp);
    float2 v1 = *(const float2*)(rp+2);
    float s = v0.x+v0.y+v1.x+v1.y;
    float ss = v0.x*v0.x+v0.y*v0.y+v1.x*v1.x+v1.y*v1.y;
    #pragma unroll
    for (int o=32;o>0;o>>=1){ s += __shfl_xor(s,o,64); ss += __shfl_xor(ss,o,64); }
    if (lane==0){ float m=s*(1.f/DM); sm[rrow]=m; sr[rrow]=rsqrtf(ss*(1.f/DM)-m*m+1e-5f); }
  }
  __syncthreads();
  float gv = pg[tid], bv = pb[tid];
  for (int rrow=0;rrow<32;rrow++){
    int tok = row0 + rrow;
    float v = (sOut[rrow*SOS + tid]-sm[rrow])*sr[rrow]*gv + bv + skip[(size_t)tok*DM + tid];
    out[(size_t)tok*DM + tid] = v;
  }
}

extern "C" void kernel_launch(void* const* d_in, const int* in_sizes, int n_in,
                              void* d_out, int out_size, void* d_ws, size_t ws_size,
                              hipStream_t stream)
{
  const float* input      = (const float*)d_in[0];
  const float* norm_g     = (const float*)d_in[1];
  const float* norm_b     = (const float*)d_in[2];
  const float* in_proj_w  = (const float*)d_in[3];
  const float* conv_w     = (const float*)d_in[4];
  const float* conv_b     = (const float*)d_in[5];
  const float* xproj_w    = (const float*)d_in[6];
  const float* dtproj_w   = (const float*)d_in[7];
  const float* dtproj_b   = (const float*)d_in[8];
  const float* A_log      = (const float*)d_in[9];
  const float* Dp         = (const float*)d_in[10];
  const float* conv_w_b   = (const float*)d_in[11];
  const float* conv_b_b   = (const float*)d_in[12];
  const float* xproj_w_b  = (const float*)d_in[13];
  const float* dtproj_w_b = (const float*)d_in[14];
  const float* dtproj_b_b = (const float*)d_in[15];
  const float* A_log_b    = (const float*)d_in[16];
  const float* Dp_b       = (const float*)d_in[17];
  const float* out_norm_g = (const float*)d_in[18];
  const float* out_norm_b = (const float*)d_in[19];
  const float* out_proj_w = (const float*)d_in[20];
  const float* post_norm_g= (const float*)d_in[21];
  const float* post_norm_b= (const float*)d_in[22];
  float* out = (float*)d_out;

  float* ws = (float*)d_ws;
  const size_t M2 = (size_t)NTOK*DM;           // 2,097,152 elements
  const size_t SCH = (size_t)BT*NCHK*DM*NS;    // 4,194,304 elements per array (bf16 -> 8MB)
  // slot0 (8MB): y16f / y16b bf16
  unsigned short* y16f = (unsigned short*)ws;
  unsigned short* y16b = (unsigned short*)ws + M2;
  // slot1 (8MB): zb bf16 (4MB) + weight staging (4MB)
  unsigned short* zbuf = (unsigned short*)(ws + M2);
  unsigned short* auxw = (unsigned short*)(ws + M2 + M2/2);
  unsigned short* Wbin  = auxw;
  unsigned short* Wcatb = auxw + 131072;
  unsigned short* Wbout = auxw + 131072 + 163840;
  // slot3 (8MB): dt bf16 fwd+bwd
  unsigned short* dt16f = (unsigned short*)(ws + 3*M2);
  unsigned short* dt16b = dt16f + M2;
  // slot4 (8MB): u bf16 fwd+bwd
  unsigned short* ufb = (unsigned short*)(ws + 4*M2);
  unsigned short* ubb = ufb + M2;
  // slot5: bm/cm (2MB) then ap/hs bf16 (8MB each, 32MB total)
  float* p   = ws + 5*M2;
  float* bmf = p;              p += (size_t)NTOK*NS;
  float* cmf = p;              p += (size_t)NTOK*NS;
  float* bmb = p;              p += (size_t)NTOK*NS;
  float* cmb = p;              p += (size_t)NTOK*NS;
  unsigned short* apf = (unsigned short*)p;
  unsigned short* hsf = apf + SCH;
  unsigned short* apb = hsf + SCH;
  unsigned short* hsb = apb + SCH;
  // xl bf16 alias on apf (8MB region; ap written by scan1, xl dead by then)
  unsigned short* xlbf = apf;

  k_prep<<<NTOK/4 + 136 + 64, 256, 0, stream>>>(input, norm_g, norm_b, xlbf,
                                                in_proj_w, Wbin,
                                                xproj_w, xproj_w_b, dtproj_w, dtproj_w_b, Wcatb,
                                                out_proj_w, Wbout);
  k_inproj_conv<<<dim3(NTOK/128, 8, 1), 256, 0, stream>>>(xlbf, Wbin,
                                                          conv_w, conv_b, conv_w_b, conv_b_b,
                                                          ufb, ubb, zbuf);
  k_xproj_mfma<<<dim3(NTOK/128, 5, 2), 256, 0, stream>>>(ufb, ubb, Wcatb,
                                                         dtproj_b, dtproj_b_b,
                                                         dt16f, dt16b, bmf, cmf, bmb, cmb);
  k_scan1<<<dim3(NCHK, BT, 2), 256, 0, stream>>>(dt16f, dt16b, ufb, ubb, bmf, bmb,
                                                 A_log, A_log_b, apf, hsf, apb, hsb);
  k_scan2<<<512, 256, 0, stream>>>(apf, hsf, apb, hsb);
  k_scan3<<<dim3(NCHK, BT, 2), 256, 0, stream>>>(dt16f, dt16b, ufb, ubb, bmf, bmb, cmf, cmb,
                                                 A_log, A_log_b, Dp, Dp_b, zbuf, hsf, hsb,
                                                 y16f, y16b);
  k_final2<<<NTOK/32, 256, 0, stream>>>(y16f, y16b, out_norm_g, out_norm_b, Wbout,
                                        post_norm_g, post_norm_b, input, out);
}

// Round 18
// 133.260 us; speedup vs baseline: 1.0228x; 1.0228x over previous
//
#include <hip/hip_runtime.h>
#include <math.h>

#define DM 256
#define SQ 4096
#define BT 2
#define NS 16
#define NTOK (BT*SQ)
#define NCHK 256
#define CHL (SQ/NCHK)

typedef __attribute__((ext_vector_type(8))) short short8;
typedef __attribute__((ext_vector_type(4))) float f32x4;

__device__ __forceinline__ float sigm_(float x){ return 1.f/(1.f+__expf(-x)); }
__device__ __forceinline__ float silu_(float x){ return x*sigm_(x); }
__device__ __forceinline__ float softplus_(float x){ return (x>20.f)? x : log1pf(__expf(x)); }
__device__ __forceinline__ unsigned short f2bf(float f){
  unsigned int u = __float_as_uint(f);
  unsigned int r = (u + 0x7FFFu + ((u>>16)&1u)) >> 16;
  return (unsigned short)r;
}
__device__ __forceinline__ float bf2f(unsigned short u){
  return __uint_as_float(((unsigned int)u)<<16);
}

// ---------- prep: LN+cvt of x | in_proj W cvt | Wcat build | out_proj W cvt ----------
__global__ __launch_bounds__(256) void k_prep(
    const float* __restrict__ x, const float* __restrict__ g, const float* __restrict__ nb,
    unsigned short* __restrict__ xl,
    const float* __restrict__ Win, unsigned short* __restrict__ Wbin,
    const float* __restrict__ xw_f, const float* __restrict__ xw_b,
    const float* __restrict__ dtw_f, const float* __restrict__ dtw_b,
    unsigned short* __restrict__ Wcatb,
    const float* __restrict__ Wout, unsigned short* __restrict__ Wbout)
{
  int bx = blockIdx.x;
  int tid = threadIdx.x;
  if (bx < NTOK/4){
    int tok = bx*4 + (tid>>6);
    int lane = tid & 63;
    const float* row = x + (size_t)tok*DM;
    float4 v = *(const float4*)(row + lane*4);
    float s = v.x+v.y+v.z+v.w;
    float ss = v.x*v.x+v.y*v.y+v.z*v.z+v.w*v.w;
    #pragma unroll
    for (int o=32;o>0;o>>=1){ s += __shfl_xor(s,o,64); ss += __shfl_xor(ss,o,64); }
    float m = s*(1.f/DM);
    float r = rsqrtf(ss*(1.f/DM)-m*m+1e-5f);
    float4 gv = *(const float4*)(g + lane*4);
    float4 bv = *(const float4*)(nb + lane*4);
    ushort4 o4;
    o4.x = f2bf((v.x-m)*r*gv.x+bv.x);
    o4.y = f2bf((v.y-m)*r*gv.y+bv.y);
    o4.z = f2bf((v.z-m)*r*gv.z+bv.z);
    o4.w = f2bf((v.w-m)*r*gv.w+bv.w);
    *(ushort4*)(xl + (size_t)tok*DM + lane*4) = o4;
  } else if (bx < NTOK/4 + 128){
    int i = ((bx - NTOK/4)*256 + tid)*4;
    float4 v = *(const float4*)(Win + i);
    ushort4 o4; o4.x=f2bf(v.x); o4.y=f2bf(v.y); o4.z=f2bf(v.z); o4.w=f2bf(v.w);
    *(ushort4*)(Wbin + i) = o4;
  } else if (bx < NTOK/4 + 136){
    int idx = bx - (NTOK/4 + 128);
    int dir = idx >> 2;
    int kc = (idx & 3)*64;
    const float* xw  = dir? xw_b : xw_f;
    const float* dtw = dir? dtw_b : dtw_f;
    int d = tid;
    float dw[16];
    #pragma unroll
    for (int r=0;r<16;r++) dw[r] = dtw[d*16+r];
    unsigned short* Wd = Wcatb + (size_t)dir*320*DM + (size_t)d*DM + kc;
    for (int kk=0;kk<64;kk++){
      float acc = 0.f;
      #pragma unroll
      for (int r=0;r<16;r++) acc += dw[r]*xw[r*DM + kc + kk];
      Wd[kk] = f2bf(acc);
    }
    if (d < 64){
      unsigned short* Wr = Wcatb + (size_t)dir*320*DM + (size_t)(256+d)*DM + kc;
      if (d < 32){
        const float* src = xw + (size_t)(16+d)*DM + kc;
        for (int kk=0;kk<64;kk++) Wr[kk] = f2bf(src[kk]);
      } else {
        for (int kk=0;kk<64;kk++) Wr[kk] = 0;
      }
    }
  } else {
    int i = ((bx - (NTOK/4 + 136))*256 + tid)*4;
    float4 v = *(const float4*)(Wout + i);
    ushort4 o4; o4.x=f2bf(v.x); o4.y=f2bf(v.y); o4.z=f2bf(v.z); o4.w=f2bf(v.w);
    *(ushort4*)(Wbout + i) = o4;
  }
}

// ---------- in_proj MFMA + fused causal dwconv+silu (y<4) | z bf16 (y>=4) ----------
__global__ __launch_bounds__(256) void k_inproj_conv(
    const unsigned short* __restrict__ xl, const unsigned short* __restrict__ Wb,
    const float* __restrict__ cw_f, const float* __restrict__ cb_f,
    const float* __restrict__ cw_b, const float* __restrict__ cb_b,
    unsigned short* __restrict__ ufb, unsigned short* __restrict__ ubb,
    unsigned short* __restrict__ zb)
{
  __shared__ float xs[134][68];
  __shared__ unsigned short xh[6][256];
  int tid = threadIdx.x;
  int wid = tid >> 6, lane = tid & 63;
  int wm = wid >> 1, wn = wid & 1;
  int row0 = blockIdx.x*128 + wm*64;
  int col0 = blockIdx.y*64 + wn*32;
  int lr = lane & 15, lg = lane >> 4;
  f32x4 acc[4][2];
  #pragma unroll
  for (int m=0;m<4;m++)
    #pragma unroll
    for (int n=0;n<2;n++) acc[m][n] = (f32x4){0.f,0.f,0.f,0.f};

  #pragma unroll
  for (int k0=0;k0<DM;k0+=32){
    short8 a[4], b[2];
    #pragma unroll
    for (int m=0;m<4;m++)
      a[m] = *(const short8*)(xl + (size_t)(row0 + m*16 + lr)*DM + k0 + lg*8);
    #pragma unroll
    for (int n=0;n<2;n++)
      b[n] = *(const short8*)(Wb + (size_t)(col0 + n*16 + lr)*DM + k0 + lg*8);
    #pragma unroll
    for (int m=0;m<4;m++)
      #pragma unroll
      for (int n=0;n<2;n++)
        acc[m][n] = __builtin_amdgcn_mfma_f32_16x16x32_bf16(a[m], b[n], acc[m][n], 0,0,0);
  }
  if (blockIdx.y >= 4){
    int cb = col0 - 256;
    #pragma unroll
    for (int m=0;m<4;m++)
      #pragma unroll
      for (int n=0;n<2;n++)
        #pragma unroll
        for (int r=0;r<4;r++){
          int rr = row0 + m*16 + lg*4 + r;
          int cc = cb + n*16 + lr;
          zb[(size_t)rr*DM + cc] = f2bf(acc[m][n][r]);
        }
    return;
  }
  #pragma unroll
  for (int m=0;m<4;m++)
    #pragma unroll
    for (int n=0;n<2;n++)
      #pragma unroll
      for (int r=0;r<4;r++)
        xs[wm*64 + m*16 + lg*4 + r + 3][wn*32 + n*16 + lr] = acc[m][n][r];
  int b_  = blockIdx.x >> 5;
  int lt0 = (blockIdx.x & 31)*128;
  for (int i=tid; i<6*256; i+=256){
    int hr = i >> 8, k = i & 255;
    int lt = (hr<3)? (lt0-3+hr) : (lt0+128+(hr-3));
    unsigned short v = 0;
    if (lt >= 0 && lt < SQ) v = xl[((size_t)b_*SQ+lt)*DM + k];
    xh[hr][k] = v;
  }
  __syncthreads();
  for (int i=tid; i<384; i+=256){
    int hr = i >> 6, col = i & 63;
    int gcol = blockIdx.y*64 + col;
    float acch = 0.f;
    for (int k=0;k<256;k+=8){
      short8 xa = *(const short8*)&xh[hr][k];
      short8 wv = *(const short8*)(Wb + (size_t)gcol*DM + k);
      #pragma unroll
      for (int e=0;e<8;e++) acch += bf2f((unsigned short)xa[e])*bf2f((unsigned short)wv[e]);
    }
    int xr = (hr<3)? hr : (131 + hr - 3);
    xs[xr][col] = acch;
  }
  __syncthreads();
  int col = tid & 63, tg = tid >> 6;
  int gd = blockIdx.y*64 + col;
  float wf0=cw_f[gd*4], wf1=cw_f[gd*4+1], wf2=cw_f[gd*4+2], wf3=cw_f[gd*4+3];
  float wb0=cw_b[gd*4], wb1=cw_b[gd*4+1], wb2=cw_b[gd*4+2], wb3=cw_b[gd*4+3];
  float bfv = cb_f[gd], bbv = cb_b[gd];
  for (int i=0;i<32;i++){
    int r = tg*32 + i;
    float x0=xs[r][col], x1=xs[r+1][col], x2=xs[r+2][col], x3=xs[r+3][col];
    float vf = silu_(bfv + wf0*x0 + wf1*x1 + wf2*x2 + wf3*x3);
    ufb[((size_t)b_*SQ + lt0 + r)*DM + gd] = f2bf(vf);
    float x4=xs[r+4][col], x5=xs[r+5][col], x6=xs[r+6][col];
    float vb = silu_(bbv + wb3*x3 + wb2*x4 + wb1*x5 + wb0*x6);
    ubb[((size_t)b_*SQ + (SQ-1-(lt0+r)))*DM + gd] = f2bf(vb);
  }
}

// ---------- xproj+dtproj via MFMA: [8192][320] = u_bf16 @ Wcat^T ----------
__global__ __launch_bounds__(256) void k_xproj_mfma(
    const unsigned short* __restrict__ ufb, const unsigned short* __restrict__ ubb,
    const unsigned short* __restrict__ Wcatb,
    const float* __restrict__ dtbias_f, const float* __restrict__ dtbias_b,
    unsigned short* __restrict__ dt16f, unsigned short* __restrict__ dt16b,
    float* __restrict__ bmf, float* __restrict__ cmf,
    float* __restrict__ bmb, float* __restrict__ cmb)
{
  int dir = blockIdx.z;
  const unsigned short* u  = dir? ubb : ufb;
  const unsigned short* Wc = Wcatb + (size_t)dir*320*DM;
  const float* dbi = dir? dtbias_b : dtbias_f;
  unsigned short* dt = dir? dt16b : dt16f;
  float* bm = dir? bmb : bmf;
  float* cm = dir? cmb : cmf;
  int tid = threadIdx.x;
  int wid = tid >> 6, lane = tid & 63;
  int wm = wid >> 1, wn = wid & 1;
  int row0 = blockIdx.x*128 + wm*64;
  int col0 = blockIdx.y*64 + wn*32;
  int lr = lane & 15, lg = lane >> 4;
  f32x4 acc[4][2];
  #pragma unroll
  for (int m=0;m<4;m++)
    #pragma unroll
    for (int n=0;n<2;n++) acc[m][n] = (f32x4){0.f,0.f,0.f,0.f};
  #pragma unroll
  for (int k0=0;k0<DM;k0+=32){
    short8 a[4], b[2];
    #pragma unroll
    for (int m=0;m<4;m++)
      a[m] = *(const short8*)(u + (size_t)(row0 + m*16 + lr)*DM + k0 + lg*8);
    #pragma unroll
    for (int n=0;n<2;n++)
      b[n] = *(const short8*)(Wc + (size_t)(col0 + n*16 + lr)*DM + k0 + lg*8);
    #pragma unroll
    for (int m=0;m<4;m++)
      #pragma unroll
      for (int n=0;n<2;n++)
        acc[m][n] = __builtin_amdgcn_mfma_f32_16x16x32_bf16(a[m], b[n], acc[m][n], 0,0,0);
  }
  if (blockIdx.y < 4){
    #pragma unroll
    for (int n=0;n<2;n++){
      int cc = col0 + n*16 + lr;
      float bias = dbi[cc];
      #pragma unroll
      for (int m=0;m<4;m++)
        #pragma unroll
        for (int r=0;r<4;r++){
          int rr = row0 + m*16 + lg*4 + r;
          dt[(size_t)rr*DM + cc] = f2bf(softplus_(acc[m][n][r] + bias));
        }
    }
  } else if (wn == 0){
    #pragma unroll
    for (int n=0;n<2;n++){
      float* outp = n ? cm : bm;
      #pragma unroll
      for (int m=0;m<4;m++)
        #pragma unroll
        for (int r=0;r<4;r++){
          int rr = row0 + m*16 + lg*4 + r;
          outp[(size_t)rr*NS + lr] = acc[m][n][r];
        }
    }
  }
}

// power-tree: given w, fill e[n] = w^(n+1) for n=0..15 (depth ~3)
__device__ __forceinline__ void pow16_(float w, float* e){
  float w2 = w*w, w4 = w2*w2, w8 = w4*w4;
  float w3 = w2*w;
  e[0]=w;      e[1]=w2;     e[2]=w3;     e[3]=w4;
  e[4]=w4*w;   e[5]=w4*w2;  e[6]=w4*w3;  e[7]=w8;
  e[8]=w8*w;   e[9]=w8*w2;  e[10]=w8*w3; e[11]=w8*w4;
  e[12]=w8*e[4]; e[13]=w8*e[5]; e[14]=w8*e[6]; e[15]=w8*w8;
}

// ---------- scan phase 1: per-chunk summaries (Aprod, h_end) -> bf16 ----------
__global__ __launch_bounds__(256) void k_scan1(
    const unsigned short* __restrict__ dtf, const unsigned short* __restrict__ dtb,
    const unsigned short* __restrict__ ufb, const unsigned short* __restrict__ ubb,
    const float* __restrict__ bmf, const float* __restrict__ bmb,
    const float* __restrict__ alog_f, const float* __restrict__ alog_b,
    unsigned short* __restrict__ apf, unsigned short* __restrict__ hsf,
    unsigned short* __restrict__ apb, unsigned short* __restrict__ hsb)
{
  int c = blockIdx.x, b = blockIdx.y, dir = blockIdx.z;
  const unsigned short* dt = dir? dtb : dtf;
  const unsigned short* u  = dir? ubb : ufb;
  const float* bmp= dir? bmb : bmf;
  const float* al = dir? alog_b : alog_f;
  unsigned short* ap = dir? apb : apf;
  unsigned short* hs = dir? hsb : hsf;
  int d = threadIdx.x;
  __shared__ float sB[CHL*NS];
  for (int i=threadIdx.x;i<CHL*NS;i+=256) sB[i] = bmp[((size_t)b*SQ + c*CHL)*NS + i];
  float A[NS];
  #pragma unroll
  for (int n=0;n<NS;n++) A[n] = -__expf(al[d*NS+n]);
  float A0 = A[0];
  bool pw = true;
  #pragma unroll
  for (int n=0;n<NS;n++)
    pw = pw && (fabsf(A[n] - (float)(n+1)*A0) <= 1e-4f*(float)(n+1)*fabsf(A0));
  float h[NS] = {};
  float dts = 0.f;
  __syncthreads();
  size_t base = ((size_t)b*SQ + c*CHL)*DM + d;
  if (pw){
    for (int t=0;t<CHL;t++){
      size_t idx = base + (size_t)t*DM;
      float dtv = bf2f(dt[idx]);
      float uv  = bf2f(u[idx]);
      float du  = dtv*uv;
      dts += dtv;
      float e[NS];
      pow16_(__expf(dtv*A0), e);
      #pragma unroll
      for (int n=0;n<NS;n++) h[n] = h[n]*e[n] + du*sB[t*NS+n];
    }
  } else {
    for (int t=0;t<CHL;t++){
      size_t idx = base + (size_t)t*DM;
      float dtv = bf2f(dt[idx]);
      float uv  = bf2f(u[idx]);
      float du  = dtv*uv;
      dts += dtv;
      #pragma unroll
      for (int n=0;n<NS;n++) h[n] = h[n]*__expf(dtv*A[n]) + du*sB[t*NS+n];
    }
  }
  size_t o = (((size_t)b*NCHK + c)*DM + d)*NS;
  #pragma unroll
  for (int n=0;n<NS;n++){ hs[o+n] = f2bf(h[n]); ap[o+n] = f2bf(__expf(A[n]*dts)); }
}

// ---------- scan phase 2: parallel segmented scan (32 chains/block, 8 segments) ----------
__global__ __launch_bounds__(256) void k_scan2(
    const unsigned short* __restrict__ apf, unsigned short* __restrict__ hsf,
    const unsigned short* __restrict__ apb, unsigned short* __restrict__ hsb)
{
  __shared__ float sa[NCHK][32];
  __shared__ float sv[NCHK][32];
  __shared__ float segA[8][32], segV[8][32];
  int bx = blockIdx.x;
  int dg = bx & 127, b = (bx>>7)&1, dir = bx>>8;
  const unsigned short* ap = dir? apb : apf;
  unsigned short* hs = dir? hsb : hsf;
  int dn = threadIdx.x & 31;
  int cg = threadIdx.x >> 5;          // 0..7: segment of 32 chunks
  size_t base = (size_t)b*NCHK*4096 + dg*32 + dn;
  for (int i=0;i<32;i++){
    int c = cg*32 + i;
    size_t idx = base + (size_t)c*4096;
    sa[c][dn] = bf2f(ap[idx]);
    sv[c][dn] = bf2f(hs[idx]);
  }
  __syncthreads();
  float A = 1.f, V = 0.f;
  for (int i=0;i<32;i++){
    int c = cg*32 + i;
    float a = sa[c][dn], v = sv[c][dn];
    V = a*V + v;
    A = A*a;
  }
  segA[cg][dn] = A; segV[cg][dn] = V;
  __syncthreads();
  float pre = 0.f;
  for (int s=0;s<cg;s++) pre = segA[s][dn]*pre + segV[s][dn];
  float xv = pre;
  for (int i=0;i<32;i++){
    int c = cg*32 + i;
    size_t idx = base + (size_t)c*4096;
    hs[idx] = f2bf(xv);
    float a = sa[c][dn], v = sv[c][dn];
    xv = a*xv + v;
  }
}

// ---------- scan phase 3: replay with prefix, emit y bf16 (both dirs, one dispatch) ----------
__global__ __launch_bounds__(256) void k_scan3(
    const unsigned short* __restrict__ dtf, const unsigned short* __restrict__ dtb,
    const unsigned short* __restrict__ ufb, const unsigned short* __restrict__ ubb,
    const float* __restrict__ bmf, const float* __restrict__ bmb,
    const float* __restrict__ cmf, const float* __restrict__ cmb,
    const float* __restrict__ alf, const float* __restrict__ alb,
    const float* __restrict__ Df, const float* __restrict__ Db,
    const unsigned short* __restrict__ zb,
    const unsigned short* __restrict__ hsf, const unsigned short* __restrict__ hsb,
    unsigned short* __restrict__ yf, unsigned short* __restrict__ yb)
{
  int c = blockIdx.x, b = blockIdx.y;
  int dir = blockIdx.z;
  const unsigned short* dt = dir? dtb : dtf;
  const unsigned short* u  = dir? ubb : ufb;
  const float* bmp= dir? bmb : bmf;
  const float* cmp= dir? cmb : cmf;
  const float* al = dir? alb : alf;
  const float* Dv = dir? Db  : Df;
  const unsigned short* hs = dir? hsb : hsf;
  unsigned short* yout = dir? yb : yf;
  int d = threadIdx.x;
  __shared__ float sB[CHL*NS];
  __shared__ float sC[CHL*NS];
  for (int i=threadIdx.x;i<CHL*NS;i+=256){
    sB[i] = bmp[((size_t)b*SQ + c*CHL)*NS + i];
    sC[i] = cmp[((size_t)b*SQ + c*CHL)*NS + i];
  }
  float A[NS], h[NS];
  size_t o = (((size_t)b*NCHK + c)*DM + d)*NS;
  #pragma unroll
  for (int n=0;n<NS;n++){ A[n] = -__expf(al[d*NS+n]); h[n] = bf2f(hs[o+n]); }
  float A0 = A[0];
  bool pw = true;
  #pragma unroll
  for (int n=0;n<NS;n++)
    pw = pw && (fabsf(A[n] - (float)(n+1)*A0) <= 1e-4f*(float)(n+1)*fabsf(A0));
  float Dd = Dv[d];
  __syncthreads();
  if (pw){
    for (int t=0;t<CHL;t++){
      int gt = c*CHL + t;
      size_t idx = ((size_t)b*SQ + gt)*DM + d;
      float dtv = bf2f(dt[idx]);
      float uv  = bf2f(u[idx]);
      float du  = dtv*uv;
      float e[NS];
      pow16_(__expf(dtv*A0), e);
      float y = 0.f;
      #pragma unroll
      for (int n=0;n<NS;n++){
        h[n] = h[n]*e[n] + du*sB[t*NS+n];
        y += h[n]*sC[t*NS+n];
      }
      y += uv*Dd;
      int torig = dir ? (SQ-1-gt) : gt;
      size_t oidx = ((size_t)b*SQ + torig)*DM + d;
      float zv = bf2f(zb[oidx]);
      yout[oidx] = f2bf(y * (zv * sigm_(zv)));
    }
  } else {
    for (int t=0;t<CHL;t++){
      int gt = c*CHL + t;
      size_t idx = ((size_t)b*SQ + gt)*DM + d;
      float dtv = bf2f(dt[idx]);
      float uv  = bf2f(u[idx]);
      float du  = dtv*uv;
      float y = 0.f;
      #pragma unroll
      for (int n=0;n<NS;n++){
        h[n] = h[n]*__expf(dtv*A[n]) + du*sB[t*NS+n];
        y += h[n]*sC[t*NS+n];
      }
      y += uv*Dd;
      int torig = dir ? (SQ-1-gt) : gt;
      size_t oidx = ((size_t)b*SQ + torig)*DM + d;
      float zv = bf2f(zb[oidx]);
      yout[oidx] = f2bf(y * (zv * sigm_(zv)));
    }
  }
}

// ---------- final: y-combine + out-LN (in LDS) + MFMA out_proj + post-LN + skip ----------
#define SOS 266
__global__ __launch_bounds__(256) void k_final2(
    const unsigned short* __restrict__ y16f, const unsigned short* __restrict__ y16b,
    const float* __restrict__ og, const float* __restrict__ ob,
    const unsigned short* __restrict__ Wb,
    const float* __restrict__ pg, const float* __restrict__ pb,
    const float* __restrict__ skip, float* __restrict__ out)
{
  __shared__ unsigned short yn[32][272];
  __shared__ float sOut[32*SOS];
  __shared__ float sm[32], sr[32];
  int tid = threadIdx.x;
  int wid = tid >> 6, lane = tid & 63;
  int row0 = blockIdx.x*32;
  for (int j=0;j<8;j++){
    int rrow = wid*8 + j;
    size_t base = (size_t)(row0+rrow)*DM + lane*4;
    ushort4 hf = *(const ushort4*)(y16f + base);
    ushort4 hb = *(const ushort4*)(y16b + base);
    float4 v;
    v.x = 0.5f*(bf2f(hf.x)+bf2f(hb.x));
    v.y = 0.5f*(bf2f(hf.y)+bf2f(hb.y));
    v.z = 0.5f*(bf2f(hf.z)+bf2f(hb.z));
    v.w = 0.5f*(bf2f(hf.w)+bf2f(hb.w));
    float s = v.x+v.y+v.z+v.w;
    float ss = v.x*v.x+v.y*v.y+v.z*v.z+v.w*v.w;
    #pragma unroll
    for (int o=32;o>0;o>>=1){ s += __shfl_xor(s,o,64); ss += __shfl_xor(ss,o,64); }
    float m = s*(1.f/DM);
    float r = rsqrtf(ss*(1.f/DM)-m*m+1e-5f);
    float4 gv = *(const float4*)(og + lane*4);
    float4 bv = *(const float4*)(ob + lane*4);
    ushort4 o4;
    o4.x = f2bf((v.x-m)*r*gv.x+bv.x);
    o4.y = f2bf((v.y-m)*r*gv.y+bv.y);
    o4.z = f2bf((v.z-m)*r*gv.z+bv.z);
    o4.w = f2bf((v.w-m)*r*gv.w+bv.w);
    *(ushort4*)&yn[rrow][lane*4] = o4;
  }
  __syncthreads();
  int lr = lane & 15, lg = lane >> 4;
  int col0 = wid*64;
  f32x4 acc[2][4];
  #pragma unroll
  for (int m=0;m<2;m++)
    #pragma unroll
    for (int n=0;n<4;n++) acc[m][n] = (f32x4){0.f,0.f,0.f,0.f};
  #pragma unroll
  for (int k0=0;k0<DM;k0+=32){
    short8 a[2], b[4];
    #pragma unroll
    for (int m=0;m<2;m++)
      a[m] = *(const short8*)&yn[m*16 + lr][k0 + lg*8];
    #pragma unroll
    for (int n=0;n<4;n++)
      b[n] = *(const short8*)(Wb + (size_t)(col0 + n*16 + lr)*DM + k0 + lg*8);
    #pragma unroll
    for (int m=0;m<2;m++)
      #pragma unroll
      for (int n=0;n<4;n++)
        acc[m][n] = __builtin_amdgcn_mfma_f32_16x16x32_bf16(a[m], b[n], acc[m][n], 0,0,0);
  }
  #pragma unroll
  for (int m=0;m<2;m++)
    #pragma unroll
    for (int n=0;n<4;n++)
      #pragma unroll
      for (int r=0;r<4;r++)
        sOut[(m*16 + lg*4 + r)*SOS + col0 + n*16 + lr] = acc[m][n][r];
  __syncthreads();
  for (int j=0;j<8;j++){
    int rrow = wid*8 + j;
    const float* rp = &sOut[rrow*SOS + lane*4];
    float2 v0 = *(const float2*)(rp);
    float2 v1 = *(const float2*)(rp+2);
    float s = v0.x+v0.y+v1.x+v1.y;
    float ss = v0.x*v0.x+v0.y*v0.y+v1.x*v1.x+v1.y*v1.y;
    #pragma unroll
    for (int o=32;o>0;o>>=1){ s += __shfl_xor(s,o,64); ss += __shfl_xor(ss,o,64); }
    if (lane==0){ float m=s*(1.f/DM); sm[rrow]=m; sr[rrow]=rsqrtf(ss*(1.f/DM)-m*m+1e-5f); }
  }
  __syncthreads();
  float gv = pg[tid], bv = pb[tid];
  for (int rrow=0;rrow<32;rrow++){
    int tok = row0 + rrow;
    float v = (sOut[rrow*SOS + tid]-sm[rrow])*sr[rrow]*gv + bv + skip[(size_t)tok*DM + tid];
    out[(size_t)tok*DM + tid] = v;
  }
}

extern "C" void kernel_launch(void* const* d_in, const int* in_sizes, int n_in,
                              void* d_out, int out_size, void* d_ws, size_t ws_size,
                              hipStream_t stream)
{
  const float* input      = (const float*)d_in[0];
  const float* norm_g     = (const float*)d_in[1];
  const float* norm_b     = (const float*)d_in[2];
  const float* in_proj_w  = (const float*)d_in[3];
  const float* conv_w     = (const float*)d_in[4];
  const float* conv_b     = (const float*)d_in[5];
  const float* xproj_w    = (const float*)d_in[6];
  const float* dtproj_w   = (const float*)d_in[7];
  const float* dtproj_b   = (const float*)d_in[8];
  const float* A_log      = (const float*)d_in[9];
  const float* Dp         = (const float*)d_in[10];
  const float* conv_w_b   = (const float*)d_in[11];
  const float* conv_b_b   = (const float*)d_in[12];
  const float* xproj_w_b  = (const float*)d_in[13];
  const float* dtproj_w_b = (const float*)d_in[14];
  const float* dtproj_b_b = (const float*)d_in[15];
  const float* A_log_b    = (const float*)d_in[16];
  const float* Dp_b       = (const float*)d_in[17];
  const float* out_norm_g = (const float*)d_in[18];
  const float* out_norm_b = (const float*)d_in[19];
  const float* out_proj_w = (const float*)d_in[20];
  const float* post_norm_g= (const float*)d_in[21];
  const float* post_norm_b= (const float*)d_in[22];
  float* out = (float*)d_out;

  float* ws = (float*)d_ws;
  const size_t M2 = (size_t)NTOK*DM;           // 2,097,152 elements
  const size_t SCH = (size_t)BT*NCHK*DM*NS;    // 4,194,304 elements per array (bf16 -> 8MB)
  // slot0 (8MB): y16f / y16b bf16
  unsigned short* y16f = (unsigned short*)ws;
  unsigned short* y16b = (unsigned short*)ws + M2;
  // slot1 (8MB): zb bf16 (4MB) + weight staging (4MB)
  unsigned short* zbuf = (unsigned short*)(ws + M2);
  unsigned short* auxw = (unsigned short*)(ws + M2 + M2/2);
  unsigned short* Wbin  = auxw;
  unsigned short* Wcatb = auxw + 131072;
  unsigned short* Wbout = auxw + 131072 + 163840;
  // slot3 (8MB): dt bf16 fwd+bwd
  unsigned short* dt16f = (unsigned short*)(ws + 3*M2);
  unsigned short* dt16b = dt16f + M2;
  // slot4 (8MB): u bf16 fwd+bwd
  unsigned short* ufb = (unsigned short*)(ws + 4*M2);
  unsigned short* ubb = ufb + M2;
  // slot5: bm/cm (2MB) then ap/hs bf16 (8MB each, 32MB total)
  float* p   = ws + 5*M2;
  float* bmf = p;              p += (size_t)NTOK*NS;
  float* cmf = p;              p += (size_t)NTOK*NS;
  float* bmb = p;              p += (size_t)NTOK*NS;
  float* cmb = p;              p += (size_t)NTOK*NS;
  unsigned short* apf = (unsigned short*)p;
  unsigned short* hsf = apf + SCH;
  unsigned short* apb = hsf + SCH;
  unsigned short* hsb = apb + SCH;
  // xl bf16 alias on apf (8MB region; ap written by scan1, xl dead by then)
  unsigned short* xlbf = apf;

  k_prep<<<NTOK/4 + 136 + 64, 256, 0, stream>>>(input, norm_g, norm_b, xlbf,
                                                in_proj_w, Wbin,
                                                xproj_w, xproj_w_b, dtproj_w, dtproj_w_b, Wcatb,
                                                out_proj_w, Wbout);
  k_inproj_conv<<<dim3(NTOK/128, 8, 1), 256, 0, stream>>>(xlbf, Wbin,
                                                          conv_w, conv_b, conv_w_b, conv_b_b,
                                                          ufb, ubb, zbuf);
  k_xproj_mfma<<<dim3(NTOK/128, 5, 2), 256, 0, stream>>>(ufb, ubb, Wcatb,
                                                         dtproj_b, dtproj_b_b,
                                                         dt16f, dt16b, bmf, cmf, bmb, cmb);
  k_scan1<<<dim3(NCHK, BT, 2), 256, 0, stream>>>(dt16f, dt16b, ufb, ubb, bmf, bmb,
                                                 A_log, A_log_b, apf, hsf, apb, hsb);
  k_scan2<<<512, 256, 0, stream>>>(apf, hsf, apb, hsb);
  k_scan3<<<dim3(NCHK, BT, 2), 256, 0, stream>>>(dt16f, dt16b, ufb, ubb, bmf, bmb, cmf, cmb,
                                                 A_log, A_log_b, Dp, Dp_b, zbuf, hsf, hsb,
                                                 y16f, y16b);
  k_final2<<<NTOK/32, 256, 0, stream>>>(y16f, y16b, out_norm_g, out_norm_b, Wbout,
                                        post_norm_g, post_norm_b, input, out);
}